// Round 2
// baseline (824.630 us; speedup 1.0000x reference)
//
#include <hip/hip_runtime.h>
#include <hip/hip_fp16.h>
#include <math.h>

// Workspace layout (floats)
#define WS_CNT  0                      // 1 int    last-finisher counter (memset 0 each launch)
#define WS_PART 65536                  // 524288  gemm1 split-K partials (256 x 2048)
#define WS_POLY (65536 + 524288)       // 8000    current polygons [4][20][50][2]
#define WS_P2T  1048576                // __half p2t [4][65536 px][256 ch] = 134 MB

// ---------------- Kernel 0: FUSED
//   blockIdx <  256 : pool(p4)+GEMM1 split-K chunk; LAST finisher block also runs
//                     g1b+g2+g3 (h1/h2 kept in LDS) -> init polygons. All hidden
//                     under the HBM-bound transpose.
//   blockIdx >= 256 : one 64ch x 64px transpose tile  p2 CHW fp32 -> HWC fp16
__global__ void __launch_bounds__(512) fused_tp_g1a(
    const float* __restrict__ p2, __half* __restrict__ p2th,
    const float* __restrict__ p4, const float* __restrict__ iw1,
    const float* __restrict__ ib1,
    const float* __restrict__ iw2, const float* __restrict__ ib2,
    const float* __restrict__ iw3, const float* __restrict__ ib3,
    float* __restrict__ part, int* __restrict__ cnt,
    float* __restrict__ out_init, float* __restrict__ poly) {
    __shared__ __align__(16) float smem[6144];   // transpose tile(4160) / sf(256) / h1s(2048)+h2s(4096)
    __shared__ int isLast;
    int tid = threadIdx.x;

    if (blockIdx.x < 256) {
        // ---- pool (AdaptiveAvgPool2d(8) for channel kb) + gemm1 split-K chunk kb
        int kb = blockIdx.x;           // == channel c; k-range [kb*64, kb*64+64)
        float* sf = smem;              // [4][64]: sf[b*64 + ij]
        if (tid < 256) {
            int b = tid >> 6, ij = tid & 63;
            const float* base = p4 + (((size_t)(b * 256 + kb) * 64 + (ij >> 3) * 8) * 64 + (ij & 7) * 8);
            float s = 0.f;
            #pragma unroll
            for (int u = 0; u < 8; ++u) {
                const float4* r = (const float4*)(base + u * 64);
                float4 a = r[0], bb = r[1];
                s += a.x + a.y + a.z + a.w + bb.x + bb.y + bb.z + bb.w;
            }
            sf[tid] = s * (1.0f / 64.0f);
        }
        __syncthreads();
        float a0 = 0.f, a1 = 0.f, a2 = 0.f, a3 = 0.f;
        int kbase = kb << 6;
        for (int k = 0; k < 64; ++k) {
            float w = iw1[(size_t)(kbase + k) * 512 + tid];
            a0 = fmaf(sf[k],       w, a0);
            a1 = fmaf(sf[64 + k],  w, a1);
            a2 = fmaf(sf[128 + k], w, a2);
            a3 = fmaf(sf[192 + k], w, a3);
        }
        float* pp = part + (size_t)kb * 2048;
        pp[tid] = a0; pp[512 + tid] = a1; pp[1024 + tid] = a2; pp[1536 + tid] = a3;

        // ---- last-finisher election (device-scope release/acquire)
        __threadfence();               // each thread: make its part-stores visible
        __syncthreads();
        if (tid == 0) {
            int old = atomicAdd(cnt, 1);
            isLast = (old == 255);
        }
        __syncthreads();
        if (!isLast) return;
        __threadfence();               // acquire: see all blocks' part-stores

        // ---- g1b: reduce 256 partial chunks -> h1 (LDS), +bias, relu
        float* h1s = smem;             // 2048 floats
        float* h2s = smem + 2048;      // 4096 floats
        {
            int o0 = tid * 4;          // 0..2044
            float4 acc = make_float4(0.f, 0.f, 0.f, 0.f);
            for (int k2 = 0; k2 < 256; ++k2) {
                float4 p = *(const float4*)&part[(size_t)k2 * 2048 + o0];
                acc.x += p.x; acc.y += p.y; acc.z += p.z; acc.w += p.w;
            }
            float4 bb = *(const float4*)&ib1[o0 & 511];
            h1s[o0 + 0] = fmaxf(acc.x + bb.x, 0.f);
            h1s[o0 + 1] = fmaxf(acc.y + bb.y, 0.f);
            h1s[o0 + 2] = fmaxf(acc.z + bb.z, 0.f);
            h1s[o0 + 3] = fmaxf(acc.w + bb.w, 0.f);
        }
        __syncthreads();
        // ---- g2: h1[4x512] @ iw2[512x1024] -> h2 (LDS), +bias, relu
        {
            int j0 = tid * 2;          // 0..1022
            float2 bb = *(const float2*)&ib2[j0];
            float2 a0v = bb, a1v = bb, a2v = bb, a3v = bb;
            for (int k = 0; k < 512; ++k) {
                float2 w = *(const float2*)&iw2[(size_t)k * 1024 + j0];
                float h0 = h1s[k], h1v = h1s[512 + k], h2v = h1s[1024 + k], h3 = h1s[1536 + k];
                a0v.x = fmaf(h0, w.x, a0v.x); a0v.y = fmaf(h0, w.y, a0v.y);
                a1v.x = fmaf(h1v, w.x, a1v.x); a1v.y = fmaf(h1v, w.y, a1v.y);
                a2v.x = fmaf(h2v, w.x, a2v.x); a2v.y = fmaf(h2v, w.y, a2v.y);
                a3v.x = fmaf(h3, w.x, a3v.x); a3v.y = fmaf(h3, w.y, a3v.y);
            }
            __syncthreads();           // h1s reads done before h2s overwrite? (disjoint) -- keep order safe
            h2s[j0] = fmaxf(a0v.x, 0.f); h2s[j0 + 1] = fmaxf(a0v.y, 0.f);
            h2s[1024 + j0] = fmaxf(a1v.x, 0.f); h2s[1024 + j0 + 1] = fmaxf(a1v.y, 0.f);
            h2s[2048 + j0] = fmaxf(a2v.x, 0.f); h2s[2048 + j0 + 1] = fmaxf(a2v.y, 0.f);
            h2s[3072 + j0] = fmaxf(a3v.x, 0.f); h2s[3072 + j0 + 1] = fmaxf(a3v.y, 0.f);
        }
        __syncthreads();
        // ---- g3: h2[4x1024] @ iw3[1024x2000] -> sigmoid -> init polys
        if (tid < 500) {
            int j0 = tid * 4;          // 0..1996
            float4 bb = *(const float4*)&ib3[j0];
            float4 acc[4] = {bb, bb, bb, bb};
            for (int k = 0; k < 1024; ++k) {
                float4 w = *(const float4*)&iw3[(size_t)k * 2000 + j0];
                #pragma unroll
                for (int b = 0; b < 4; ++b) {
                    float hv = h2s[b * 1024 + k];
                    acc[b].x = fmaf(hv, w.x, acc[b].x);
                    acc[b].y = fmaf(hv, w.y, acc[b].y);
                    acc[b].z = fmaf(hv, w.z, acc[b].z);
                    acc[b].w = fmaf(hv, w.w, acc[b].w);
                }
            }
            #pragma unroll
            for (int b = 0; b < 4; ++b) {
                float4 s;
                s.x = 1.f / (1.f + expf(-acc[b].x));
                s.y = 1.f / (1.f + expf(-acc[b].y));
                s.z = 1.f / (1.f + expf(-acc[b].z));
                s.w = 1.f / (1.f + expf(-acc[b].w));
                int o = b * 2000 + j0;
                *(float4*)&out_init[o] = s;
                *(float4*)&poly[o] = s;
            }
        }
    } else {
        // ---- transpose tile (512 threads)
        int tile = blockIdx.x - 256;   // 0..16383
        int b  = tile >> 12;
        int ct = (tile >> 10) & 3;
        int xt = tile & 1023;
        int c0 = ct << 6, yx0 = xt << 6;
        float (*t)[65] = (float (*)[65])smem;   // [px_local][c_local]

        int jv = (tid & 15) << 2;               // pixel offset (4 px via float4)
        const float* ip = p2 + (((size_t)(b * 256 + c0)) << 16) + yx0;
        #pragma unroll
        for (int ii = tid >> 4; ii < 64; ii += 32) {   // channel rows, 2 iters
            float4 v = *(const float4*)(ip + ((size_t)ii << 16) + jv);
            t[jv + 0][ii] = v.x; t[jv + 1][ii] = v.y;
            t[jv + 2][ii] = v.z; t[jv + 3][ii] = v.w;
        }
        __syncthreads();
        int cl = (tid & 7) << 3;                // 8 channels
        int jj = tid >> 3;                      // pixel row 0..63
        union { __half h[8]; float4 f; } u;
        #pragma unroll
        for (int q = 0; q < 8; ++q) u.h[q] = __float2half(t[jj][cl + q]);
        *(float4*)(p2th + ((size_t)b << 24) + ((size_t)(yx0 + jj) << 8) + c0 + cl) = u.f;
    }
}

// ---------------- Kernel 5: refinement step, 16 pts/block, 4x4 register tiles
// (best-measured config: 250 blocks; per-block weight re-read minimized)
__global__ void __launch_bounds__(256) step_k(
    const __half* __restrict__ p2th,
    const float* __restrict__ rw1, const float* __restrict__ rb1,
    const float* __restrict__ rw2, const float* __restrict__ rb2,
    const float* __restrict__ rw3, const float* __restrict__ rb3,
    float* __restrict__ poly) {
    __shared__ __align__(16) float s_inp[258 * 16];  // [k][pt]
    __shared__ __align__(16) float s_r1[256 * 16];   // [j][pt]
    __shared__ __align__(16) float s_r2[128 * 16];   // [j][pt]
    int tid = threadIdx.x;
    int pt0 = blockIdx.x * 16;

    // ---- gather: thread = (ch-pair tid&127, point-group tid>>7 -> 8 pts)
    {
        int ch2 = (tid & 127) << 1;
        int pgg = tid >> 7;
        float v0[8], v1[8];
        #pragma unroll
        for (int pp = 0; pp < 8; ++pp) {
            int pt = pt0 + pgg * 8 + pp;
            int b = pt / 1000;
            float cx = poly[pt * 2], cy = poly[pt * 2 + 1];
            float ix = fminf(fmaxf(cx * 256.f - 0.5f, 0.f), 255.f);
            float iy = fminf(fmaxf(cy * 256.f - 0.5f, 0.f), 255.f);
            float x0f = floorf(ix), y0f = floorf(iy);
            int x0 = (int)x0f, y0 = (int)y0f;
            int x1 = min(x0 + 1, 255), y1 = min(y0 + 1, 255);
            float wx = ix - x0f, wy = iy - y0f;
            const __half* bt = p2th + ((size_t)b << 24);
            int r0 = (y0 << 16) + (x0 << 8) + ch2;
            int r1a = (y1 << 16) + (x0 << 8) + ch2;
            int dx = (x1 - x0) << 8;
            float2 f00 = __half22float2(*(const __half2*)(bt + r0));
            float2 f01 = __half22float2(*(const __half2*)(bt + r0 + dx));
            float2 f10 = __half22float2(*(const __half2*)(bt + r1a));
            float2 f11 = __half22float2(*(const __half2*)(bt + r1a + dx));
            float t0 = f00.x + (f01.x - f00.x) * wx;
            float b0 = f10.x + (f11.x - f10.x) * wx;
            float t1 = f00.y + (f01.y - f00.y) * wx;
            float b1 = f10.y + (f11.y - f10.y) * wx;
            v0[pp] = t0 + (b0 - t0) * wy;
            v1[pp] = t1 + (b1 - t1) * wy;
        }
        float* r0p = &s_inp[ch2 * 16 + pgg * 8];
        float* r1p = &s_inp[(ch2 + 1) * 16 + pgg * 8];
        ((float4*)r0p)[0] = make_float4(v0[0], v0[1], v0[2], v0[3]);
        ((float4*)r0p)[1] = make_float4(v0[4], v0[5], v0[6], v0[7]);
        ((float4*)r1p)[0] = make_float4(v1[0], v1[1], v1[2], v1[3]);
        ((float4*)r1p)[1] = make_float4(v1[4], v1[5], v1[6], v1[7]);
        if (tid < 32) {  // coord rows 256,257
            int p = tid >> 1, d = tid & 1;
            s_inp[(256 + d) * 16 + p] = poly[(pt0 + p) * 2 + d];
        }
    }
    __syncthreads();

    // ---- r1: thread = (col-group jc=tid&63 -> 4 cols, pt-group pg=tid>>6 -> 4 pts)
    int jc = tid & 63, pg = tid >> 6;
    {
        float4 bias = *(const float4*)(rb1 + jc * 4);
        float4 acc0 = bias, acc1 = bias, acc2 = bias, acc3 = bias;
        for (int k = 0; k < 258; ++k) {
            float4 a = *(const float4*)&s_inp[k * 16 + pg * 4];
            float4 w = *(const float4*)(rw1 + k * 256 + jc * 4);
            acc0.x = fmaf(a.x, w.x, acc0.x); acc0.y = fmaf(a.x, w.y, acc0.y);
            acc0.z = fmaf(a.x, w.z, acc0.z); acc0.w = fmaf(a.x, w.w, acc0.w);
            acc1.x = fmaf(a.y, w.x, acc1.x); acc1.y = fmaf(a.y, w.y, acc1.y);
            acc1.z = fmaf(a.y, w.z, acc1.z); acc1.w = fmaf(a.y, w.w, acc1.w);
            acc2.x = fmaf(a.z, w.x, acc2.x); acc2.y = fmaf(a.z, w.y, acc2.y);
            acc2.z = fmaf(a.z, w.z, acc2.z); acc2.w = fmaf(a.z, w.w, acc2.w);
            acc3.x = fmaf(a.w, w.x, acc3.x); acc3.y = fmaf(a.w, w.y, acc3.y);
            acc3.z = fmaf(a.w, w.z, acc3.z); acc3.w = fmaf(a.w, w.w, acc3.w);
        }
        acc0.x = fmaxf(acc0.x, 0.f); acc0.y = fmaxf(acc0.y, 0.f);
        acc0.z = fmaxf(acc0.z, 0.f); acc0.w = fmaxf(acc0.w, 0.f);
        acc1.x = fmaxf(acc1.x, 0.f); acc1.y = fmaxf(acc1.y, 0.f);
        acc1.z = fmaxf(acc1.z, 0.f); acc1.w = fmaxf(acc1.w, 0.f);
        acc2.x = fmaxf(acc2.x, 0.f); acc2.y = fmaxf(acc2.y, 0.f);
        acc2.z = fmaxf(acc2.z, 0.f); acc2.w = fmaxf(acc2.w, 0.f);
        acc3.x = fmaxf(acc3.x, 0.f); acc3.y = fmaxf(acc3.y, 0.f);
        acc3.z = fmaxf(acc3.z, 0.f); acc3.w = fmaxf(acc3.w, 0.f);
        *(float4*)&s_r1[(jc * 4 + 0) * 16 + pg * 4] = make_float4(acc0.x, acc1.x, acc2.x, acc3.x);
        *(float4*)&s_r1[(jc * 4 + 1) * 16 + pg * 4] = make_float4(acc0.y, acc1.y, acc2.y, acc3.y);
        *(float4*)&s_r1[(jc * 4 + 2) * 16 + pg * 4] = make_float4(acc0.z, acc1.z, acc2.z, acc3.z);
        *(float4*)&s_r1[(jc * 4 + 3) * 16 + pg * 4] = make_float4(acc0.w, acc1.w, acc2.w, acc3.w);
    }
    __syncthreads();

    // ---- r2: thread = (2 cols jc*2, 4 pts pg), k=256
    {
        float2 bias = *(const float2*)(rb2 + jc * 2);
        float2 d0 = bias, d1 = bias, d2 = bias, d3 = bias;
        for (int k = 0; k < 256; ++k) {
            float4 a = *(const float4*)&s_r1[k * 16 + pg * 4];
            float2 w = *(const float2*)(rw2 + k * 128 + jc * 2);
            d0.x = fmaf(a.x, w.x, d0.x); d0.y = fmaf(a.x, w.y, d0.y);
            d1.x = fmaf(a.y, w.x, d1.x); d1.y = fmaf(a.y, w.y, d1.y);
            d2.x = fmaf(a.z, w.x, d2.x); d2.y = fmaf(a.z, w.y, d2.y);
            d3.x = fmaf(a.w, w.x, d3.x); d3.y = fmaf(a.w, w.y, d3.y);
        }
        d0.x = fmaxf(d0.x, 0.f); d0.y = fmaxf(d0.y, 0.f);
        d1.x = fmaxf(d1.x, 0.f); d1.y = fmaxf(d1.y, 0.f);
        d2.x = fmaxf(d2.x, 0.f); d2.y = fmaxf(d2.y, 0.f);
        d3.x = fmaxf(d3.x, 0.f); d3.y = fmaxf(d3.y, 0.f);
        *(float4*)&s_r2[(jc * 2 + 0) * 16 + pg * 4] = make_float4(d0.x, d1.x, d2.x, d3.x);
        *(float4*)&s_r2[(jc * 2 + 1) * 16 + pg * 4] = make_float4(d0.y, d1.y, d2.y, d3.y);
    }
    __syncthreads();

    // ---- r3 -> tanh -> scaled clip -> polygon update (32 outputs)
    if (tid < 32) {
        int p = tid >> 1, d = tid & 1;
        float acc = rb3[d];
        for (int k = 0; k < 128; ++k)
            acc = fmaf(s_r2[k * 16 + p], rw3[k * 2 + d], acc);
        float disp = tanhf(acc) * 0.08f;
        disp = fminf(fmaxf(disp, -0.16f), 0.16f);
        int idx = (pt0 + p) * 2 + d;
        float nv = poly[idx] + disp;
        poly[idx] = fminf(fmaxf(nv, 0.f), 1.f);
    }
}

// ---------------- Kernel 6: validity head + final polygon copy
__global__ void valid_k(const float* __restrict__ poly,
                        const float* __restrict__ vw1, const float* __restrict__ vb1,
                        const float* __restrict__ vw2, const float* __restrict__ vb2,
                        float* __restrict__ out) {
    __shared__ float sp[100];
    __shared__ float sred[2];
    int tid = threadIdx.x;  // 128
    int row = blockIdx.x;   // 80
    if (tid < 100) {
        float v = poly[row * 100 + tid];
        sp[tid] = v;
        out[row * 100 + tid] = v;
    }
    __syncthreads();
    float acc = vb1[tid];
    for (int k = 0; k < 100; ++k)
        acc = fmaf(sp[k], vw1[k * 128 + tid], acc);
    float pr = fmaxf(acc, 0.f) * vw2[tid];
    #pragma unroll
    for (int off = 32; off > 0; off >>= 1)
        pr += __shfl_down(pr, off, 64);
    if ((tid & 63) == 0) sred[tid >> 6] = pr;
    __syncthreads();
    if (tid == 0) {
        float s = sred[0] + sred[1] + vb2[0];
        out[8000 + row] = 1.f / (1.f + expf(-s));
    }
}

extern "C" void kernel_launch(void* const* d_in, const int* in_sizes, int n_in,
                              void* d_out, int out_size, void* d_ws, size_t ws_size,
                              hipStream_t stream) {
    const float* p2  = (const float*)d_in[0];
    const float* p4  = (const float*)d_in[1];
    const float* iw1 = (const float*)d_in[2];
    const float* ib1 = (const float*)d_in[3];
    const float* iw2 = (const float*)d_in[4];
    const float* ib2 = (const float*)d_in[5];
    const float* iw3 = (const float*)d_in[6];
    const float* ib3 = (const float*)d_in[7];
    const float* rw1 = (const float*)d_in[8];
    const float* rb1 = (const float*)d_in[9];
    const float* rw2 = (const float*)d_in[10];
    const float* rb2 = (const float*)d_in[11];
    const float* rw3 = (const float*)d_in[12];
    const float* rb3 = (const float*)d_in[13];
    const float* vw1 = (const float*)d_in[14];
    const float* vb1 = (const float*)d_in[15];
    const float* vw2 = (const float*)d_in[16];
    const float* vb2 = (const float*)d_in[17];
    float* out = (float*)d_out;
    float* ws = (float*)d_ws;
    float* part = ws + WS_PART;
    float* poly = ws + WS_POLY;
    int*   cnt  = (int*)(ws + WS_CNT);
    __half* p2th = (__half*)(ws + WS_P2T);

    hipMemsetAsync(cnt, 0, sizeof(int), stream);   // counter init (captured as memset node)
    // transpose (16384 blocks) + pool/gemm1 (256 blocks) + last-finisher MLP chain,
    // all in one launch: the whole init-head hides under the HBM-bound transpose.
    fused_tp_g1a<<<16640, 512, 0, stream>>>(p2, p2th, p4, iw1, ib1, iw2, ib2,
                                            iw3, ib3, part, cnt, out + 8080, poly);
    for (int s = 0; s < 3; ++s)
        step_k<<<250, 256, 0, stream>>>(p2th, rw1, rb1, rw2, rb2, rw3, rb3, poly);
    valid_k<<<80, 128, 0, stream>>>(poly, vw1, vb1, vw2, vb2, out);
}